// Round 3
// baseline (178.359 us; speedup 1.0000x reference)
//
#include <hip/hip_runtime.h>
#include <hip/hip_bf16.h>

typedef unsigned short u16;
typedef unsigned int u32;
typedef __bf16 bf16x8 __attribute__((ext_vector_type(8)));
typedef float f32x16 __attribute__((ext_vector_type(16)));
typedef float f32x4 __attribute__((ext_vector_type(4)));

#define TEMP_INV (1.0f / 0.07f)
#define LOG2E 1.4426950408889634f

#if __has_builtin(__builtin_amdgcn_exp2f)
#define EXP2(x) __builtin_amdgcn_exp2f(x)
#else
#define EXP2(x) exp2f(x)
#endif

// element counts (f32) of the six feature matrices, concatenated
#define N_Z   524288   // 4096*128
#define N_POOL 131072  // 1024*128
#define TOT_CONV 2359296  // 4*N_Z + 2*N_POOL

// ---------------- Kernel 0: f32 -> bf16 conversion into ws ----------------
__global__ __launch_bounds__(256) void k_convert(
    const float* __restrict__ z, const float* __restrict__ spr,
    const float* __restrict__ f, const float* __restrict__ pag,
    const float* __restrict__ psp, const float* __restrict__ zmx,
    u16* __restrict__ dst) {
    size_t e0 = ((size_t)blockIdx.x * 256 + threadIdx.x) * 4;
    const float* src; size_t off;
    if (e0 < N_Z)                       { src = z;   off = e0; }
    else if (e0 < 2 * N_Z)              { src = spr; off = e0 - N_Z; }
    else if (e0 < 3 * N_Z)              { src = f;   off = e0 - 2 * N_Z; }
    else if (e0 < 3 * N_Z + N_POOL)     { src = pag; off = e0 - 3 * N_Z; }
    else if (e0 < 3 * N_Z + 2 * N_POOL) { src = psp; off = e0 - (3 * N_Z + N_POOL); }
    else                                { src = zmx; off = e0 - (3 * N_Z + 2 * N_POOL); }
    f32x4 v = *(const f32x4*)(src + off);
    ushort4 o;
    o.x = __bfloat16_as_ushort(__float2bfloat16(v[0]));
    o.y = __bfloat16_as_ushort(__float2bfloat16(v[1]));
    o.z = __bfloat16_as_ushort(__float2bfloat16(v[2]));
    o.w = __bfloat16_as_ushort(__float2bfloat16(v[3]));
    *(ushort4*)(dst + e0) = o;
}

// Load an 8-bf16 MFMA fragment: row = given, k = koff .. koff+7
__device__ __forceinline__ bf16x8 ldfrag(const u16* __restrict__ base, int row, int koff) {
    return *(const bf16x8*)(base + (size_t)row * 128 + koff);
}

// ---------------- Kernel 1: Rf[i] = max_k <f_i, PoolAg_k>, Rs[i] = max_k <s_i, PoolSp_k> ----------------
__global__ __launch_bounds__(256) void k_poolmax(
    const u16* __restrict__ f, const u16* __restrict__ spr,
    const u16* __restrict__ pag, const u16* __restrict__ psp,
    float* __restrict__ Rf, float* __restrict__ Rs) {
    int tid = threadIdx.x;
    int lane = tid & 63, w = tid >> 6;
    int half = lane >> 5, li = lane & 31;
    int i0 = blockIdx.x * 32;

    bf16x8 brf[8], brs[8];
#pragma unroll
    for (int kc = 0; kc < 8; ++kc) {
        int koff = kc * 16 + half * 8;
        brf[kc] = ldfrag(f, i0 + li, koff);
        brs[kc] = ldfrag(spr, i0 + li, koff);
    }

    float rmf = -1e30f, rms = -1e30f;
    int j0w = w * 256;
    for (int jt = 0; jt < 8; ++jt) {
        int j0 = j0w + jt * 32;
        f32x16 accf = {}; f32x16 accs = {};
#pragma unroll
        for (int kc = 0; kc < 8; ++kc) {
            int koff = kc * 16 + half * 8;
            bf16x8 paf = ldfrag(pag, j0 + li, koff);
            bf16x8 psf = ldfrag(psp, j0 + li, koff);
            accf = __builtin_amdgcn_mfma_f32_32x32x16_bf16(paf, brf[kc], accf, 0, 0, 0);
            accs = __builtin_amdgcn_mfma_f32_32x32x16_bf16(psf, brs[kc], accs, 0, 0, 0);
        }
#pragma unroll
        for (int r = 0; r < 16; ++r) {
            rmf = fmaxf(rmf, accf[r]);
            rms = fmaxf(rms, accs[r]);
        }
    }
    rmf = fmaxf(rmf, __shfl_xor(rmf, 32, 64));
    rms = fmaxf(rms, __shfl_xor(rms, 32, 64));

    __shared__ float red[2][4][32];
    if (half == 0) { red[0][w][li] = rmf; red[1][w][li] = rms; }
    __syncthreads();
    if (tid < 64) {
        int p = tid >> 5, ii = tid & 31;
        float m = red[p][0][ii];
        m = fmaxf(m, red[p][1][ii]);
        m = fmaxf(m, red[p][2][ii]);
        m = fmaxf(m, red[p][3][ii]);
        (p ? Rs : Rf)[i0 + ii] = m;
    }
}

// ---------------- Kernel 2: main fused pass ----------------
// grid = (32, 16): 128 i-rows per block (4 waves x 32 resident rows), 256-j chunk per block.
// Transposed MFMA output: lane&31 = i_loc (fixed per lane) -> 6 per-row stats in 6 VGPRs.
__global__ __launch_bounds__(256) void k_main(
    const u16* __restrict__ z, const u16* __restrict__ spr,
    const u16* __restrict__ f, const u16* __restrict__ zmix,
    const float* __restrict__ mnb,
    const float* __restrict__ Rf, const float* __restrict__ Rs,
    float* __restrict__ P /* [16][4096][8] */) {
    __shared__ u16 smem[32 * 64 * 8];  // 32 units (mat,kc) * 64 lanes * 8 bf16 = 32 KB

    int tid = threadIdx.x;
    int lane = tid & 63, w = tid >> 6;
    int half = lane >> 5, li = lane & 31;
    int i = blockIdx.x * 128 + w * 32 + li;
    int cbase = blockIdx.y * 256;

    const u16* mats[4] = { f, spr, z, zmix };

    // resident B-operand frags: B[k][n=lane&31] = feat[i][k]
    bf16x8 bres[4][8];
#pragma unroll
    for (int m = 0; m < 4; ++m)
#pragma unroll
        for (int kc = 0; kc < 8; ++kc)
            bres[m][kc] = ldfrag(mats[m], i, kc * 16 + half * 8);

    float rfi = Rf[i], rsi = Rs[i];
    const float* mrow = mnb + (size_t)(i & 255) * 4096;
    float wsum = 0.f, ones = 0.f, Az = 0.f, Ax = 0.f, Zz = 0.f, Zx = 0.f;
    const float c1 = TEMP_INV * LOG2E;

    // staging map: thread -> (row = tid>>3 in [0,32), 8-elem col chunk c16 in {tid&7, (tid&7)+8})
    int srow = tid >> 3;
    int sc8 = tid & 7;
    const bf16x8* sfr = (const bf16x8*)smem;

    for (int jt = 0; jt < 8; ++jt) {
        int j0 = cbase + jt * 32;
        __syncthreads();  // previous tile fully consumed
#pragma unroll
        for (int m = 0; m < 4; ++m) {
#pragma unroll
            for (int s = 0; s < 2; ++s) {
                int c16 = sc8 + s * 8;           // 0..15 -> cols c16*8 .. c16*8+7
                int kc = c16 >> 1;               // LDS unit k-chunk
                int le = (c16 & 1) * 32 + srow;  // lane slot within unit
                const u16* gp = mats[m] + (size_t)(j0 + srow) * 128 + c16 * 8;
                *(uint4*)(smem + ((size_t)(m * 8 + kc) * 64 + le) * 8) = *(const uint4*)gp;
            }
        }
        __syncthreads();

        // phase 1: f and s_pr sims
        f32x16 accF = {}; f32x16 accS = {};
#pragma unroll
        for (int kc = 0; kc < 8; ++kc) {
            accF = __builtin_amdgcn_mfma_f32_32x32x16_bf16(sfr[(0 * 8 + kc) * 64 + lane], bres[0][kc], accF, 0, 0, 0);
            accS = __builtin_amdgcn_mfma_f32_32x32x16_bf16(sfr[(1 * 8 + kc) * 64 + lane], bres[1][kc], accS, 0, 0, 0);
        }

        // phase 2: masks.  elem r: j_loc = (r&3) + 8*(r>>2) + 4*half  (m74/m101 C/D layout)
        float wv[16], ng[16];
#pragma unroll
        for (int q = 0; q < 4; ++q) {
            int jb = j0 + q * 8 + half * 4;
            f32x4 rfj = *(const f32x4*)(Rf + jb);
            f32x4 rsj = *(const f32x4*)(Rs + jb);
            f32x4 mb4 = *(const f32x4*)(mrow + jb);
#pragma unroll
            for (int t = 0; t < 4; ++t) {
                int r = q * 4 + t;
                int j = jb + t;
                bool nm = (j != i);
                bool mob = accF[r] > fminf(rfi, rfj[t]);
                bool meb = accS[r] > fminf(rsi, rsj[t]);
                bool mnbv = mb4[t] > 0.0f;
                float w1 = (mob && nm) ? 1.0f : 0.0f;
                float wvr = w1 + ((meb && nm) ? 0.5f : 0.0f);
                wv[r] = wvr;
                ng[r] = ((mob || mnbv) && nm) ? 1.0f : 0.0f;
                ones += w1;
                wsum += wvr;
            }
        }

        // phase 3: z and zmix sims
        f32x16 accZ = {}; f32x16 accX = {};
#pragma unroll
        for (int kc = 0; kc < 8; ++kc) {
            accZ = __builtin_amdgcn_mfma_f32_32x32x16_bf16(sfr[(2 * 8 + kc) * 64 + lane], bres[2][kc], accZ, 0, 0, 0);
            accX = __builtin_amdgcn_mfma_f32_32x32x16_bf16(sfr[(3 * 8 + kc) * 64 + lane], bres[3][kc], accX, 0, 0, 0);
        }

        // phase 4: consume.  Az = sum w*sim; Zz = sum ngl*exp((sim-1)/T)
#pragma unroll
        for (int r = 0; r < 16; ++r) {
            float lvz = accZ[r];
            float lvx = accX[r];
            Az = fmaf(wv[r], lvz, Az);
            Ax = fmaf(wv[r], lvx, Ax);
            Zz = fmaf(ng[r], EXP2(fmaf(lvz, c1, -c1)), Zz);
            Zx = fmaf(ng[r], EXP2(fmaf(lvx, c1, -c1)), Zx);
        }
    }

    // combine the two lane-halves (disjoint j sets, same i)
    wsum += __shfl_xor(wsum, 32, 64);
    ones += __shfl_xor(ones, 32, 64);
    Az += __shfl_xor(Az, 32, 64);
    Ax += __shfl_xor(Ax, 32, 64);
    Zz += __shfl_xor(Zz, 32, 64);
    Zx += __shfl_xor(Zx, 32, 64);
    if (half == 0) {
        float* pr = P + ((size_t)blockIdx.y * 4096 + i) * 8;
        f32x4 v4 = { wsum, ones, Az, Ax };
        *(f32x4*)pr = v4;
        pr[4] = Zz;
        pr[5] = Zx;
    }
}

// ---------------- Kernel 3a: per-m block means ----------------
__global__ __launch_bounds__(256) void k_final1(const float* __restrict__ P, float* __restrict__ bm) {
    int t = threadIdx.x;
    int m = blockIdx.x;
    int i = m * 256 + t;
    float wsum = 0.f, ones = 0.f, Az = 0.f, Ax = 0.f, Zz = 0.f, Zx = 0.f;
    for (int c = 0; c < 16; ++c) {
        const float* pr = P + ((size_t)c * 4096 + i) * 8;
        f32x4 a = *(const f32x4*)pr;
        wsum += a[0]; ones += a[1]; Az += a[2]; Ax += a[3];
        Zz += pr[4]; Zx += pr[5];
    }
    float dw = wsum > 0.f ? wsum : 1.0f;
    float lz = Zz > 0.f ? logf(Zz) : 0.f;   // guard (cannot occur in-spec)
    float lx = Zx > 0.f ? logf(Zx) : 0.f;
    float mlz = (TEMP_INV * Az - wsum * (TEMP_INV + lz)) / dw;
    float mlx = (TEMP_INV * Ax - wsum * (TEMP_INV + lx)) / dw;
    float si = ones > 0.f ? wsum : 0.f;
    float ci = (mlz + mlx) * si;
#pragma unroll
    for (int d = 1; d < 64; d <<= 1) {
        ci += __shfl_xor(ci, d, 64);
        si += __shfl_xor(si, d, 64);
    }
    __shared__ float rc[4], rs[4];
    int wv = t >> 6;
    if ((t & 63) == 0) { rc[wv] = ci; rs[wv] = si; }
    __syncthreads();
    if (t == 0) {
        float cs = rc[0] + rc[1] + rc[2] + rc[3];
        float ss = rs[0] + rs[1] + rs[2] + rs[3];
        bm[m] = ss > 0.f ? cs / ss : 0.f;
    }
}

// ---------------- Kernel 3b: sum 16 block means -> scalar ----------------
// Output hedge: write u32 = (bf16bits<<16)|bf16bits. Exact if d_out is read
// as bf16 (low u16); within 2^-9 rel if read as f32.
__global__ __launch_bounds__(64) void k_final2(const float* __restrict__ bm, u32* __restrict__ out) {
    int t = threadIdx.x;
    float v = (t < 16) ? bm[t] : 0.f;
#pragma unroll
    for (int d = 1; d < 16; d <<= 1) v += __shfl_xor(v, d, 64);
    if (t == 0) {
        __hip_bfloat16 hb = __float2bfloat16(-v / 32.0f);
        u32 bits = (u32)__bfloat16_as_ushort(hb);
        out[0] = (bits << 16) | bits;
    }
}

extern "C" void kernel_launch(void* const* d_in, const int* in_sizes, int n_in,
                              void* d_out, int out_size, void* d_ws, size_t ws_size,
                              hipStream_t stream) {
    const float* z   = (const float*)d_in[0];
    const float* spr = (const float*)d_in[1];
    const float* f   = (const float*)d_in[2];
    const float* pag = (const float*)d_in[3];
    const float* psp = (const float*)d_in[4];
    const float* zmx = (const float*)d_in[5];
    const float* mnb = (const float*)d_in[6];

    // ws layout (bytes): bf16 features [TOT_CONV u16], Rf[4096 f32], Rs[4096 f32],
    // P[16*4096*8 f32], bm[16 f32]  -> ~6.9 MB total
    u16* cb = (u16*)d_ws;
    u16* zb   = cb;
    u16* sprb = cb + N_Z;
    u16* fb   = cb + 2 * N_Z;
    u16* pagb = cb + 3 * N_Z;
    u16* pspb = cb + 3 * N_Z + N_POOL;
    u16* zmxb = cb + 3 * N_Z + 2 * N_POOL;
    float* Rf = (float*)(cb + TOT_CONV);
    float* Rs = Rf + 4096;
    float* P  = Rs + 4096;
    float* bm = P + (size_t)16 * 4096 * 8;

    k_convert<<<TOT_CONV / 4 / 256, 256, 0, stream>>>(z, spr, f, pag, psp, zmx, cb);
    k_poolmax<<<128, 256, 0, stream>>>(fb, sprb, pagb, pspb, Rf, Rs);
    dim3 g2(32, 16);
    k_main<<<g2, 256, 0, stream>>>(zb, sprb, fb, zmxb, mnb, Rf, Rs, P);
    k_final1<<<16, 256, 0, stream>>>(P, bm);
    k_final2<<<1, 64, 0, stream>>>(bm, (u32*)d_out);
}

// Round 4
// 173.613 us; speedup vs baseline: 1.0273x; 1.0273x over previous
//
#include <hip/hip_runtime.h>
#include <hip/hip_bf16.h>

typedef unsigned short u16;
typedef unsigned int u32;
typedef unsigned long long u64;
typedef __bf16 bf16x8 __attribute__((ext_vector_type(8)));
typedef float f32x16 __attribute__((ext_vector_type(16)));
typedef float f32x4 __attribute__((ext_vector_type(4)));

#define TEMP_INV (1.0f / 0.07f)
#define LOG2E 1.4426950408889634f

#if __has_builtin(__builtin_amdgcn_exp2f)
#define EXP2(x) __builtin_amdgcn_exp2f(x)
#else
#define EXP2(x) exp2f(x)
#endif

#define N_Z   524288    // 4096*128
#define N_POOL 131072   // 1024*128
#define TOT_CONV 2359296
#define CONV_BLKS 2304
#define ZB_BYTES 164096  // P(131072) + RfK/RsK(32768) + misc(256)
#define ZERO_BLKS 41

// ordered-key encode for atomic max on float (monotone u32 map)
__device__ __forceinline__ u32 fkey(float f) {
    u32 u = __float_as_uint(f);
    return (u & 0x80000000u) ? ~u : (u | 0x80000000u);
}
__device__ __forceinline__ float keyf(u32 k) {
    u32 u = (k & 0x80000000u) ? (k ^ 0x80000000u) : ~k;
    return __uint_as_float(u);
}

// global fragment load: row-major [.,128], lane pattern row, k = koff..koff+7
__device__ __forceinline__ bf16x8 ldfrag(const u16* __restrict__ base, int row, int koff) {
    return *(const bf16x8*)(base + (size_t)row * 128 + koff);
}

// ---------------- Kernel 0: f32->bf16 convert + zero P/keys/accum/ticket ----------------
__global__ __launch_bounds__(256) void k_convert(
    const float* __restrict__ z, const float* __restrict__ spr,
    const float* __restrict__ f, const float* __restrict__ pag,
    const float* __restrict__ psp, const float* __restrict__ zmx,
    u16* __restrict__ dst) {
    int bid = blockIdx.x;
    if (bid >= CONV_BLKS) {
        size_t byte = ((size_t)(bid - CONV_BLKS) * 256 + threadIdx.x) * 16;
        if (byte < ZB_BYTES) {
            uint4 zero = {0, 0, 0, 0};
            *(uint4*)((char*)(dst + TOT_CONV) + byte) = zero;
        }
        return;
    }
    size_t e0 = ((size_t)bid * 256 + threadIdx.x) * 4;
    const float* src; size_t off;
    if (e0 < N_Z)                       { src = z;   off = e0; }
    else if (e0 < 2 * N_Z)              { src = spr; off = e0 - N_Z; }
    else if (e0 < 3 * N_Z)              { src = f;   off = e0 - 2 * N_Z; }
    else if (e0 < 3 * N_Z + N_POOL)     { src = pag; off = e0 - 3 * N_Z; }
    else if (e0 < 3 * N_Z + 2 * N_POOL) { src = psp; off = e0 - (3 * N_Z + N_POOL); }
    else                                { src = zmx; off = e0 - (3 * N_Z + 2 * N_POOL); }
    f32x4 v = *(const f32x4*)(src + off);
    ushort4 o;
    o.x = __bfloat16_as_ushort(__float2bfloat16(v[0]));
    o.y = __bfloat16_as_ushort(__float2bfloat16(v[1]));
    o.z = __bfloat16_as_ushort(__float2bfloat16(v[2]));
    o.w = __bfloat16_as_ushort(__float2bfloat16(v[3]));
    *(ushort4*)(dst + e0) = o;
}

// ---------------- Kernel 1: pool maxes -> ordered-key atomicMax ----------------
// grid (128, 2): 32 feat rows per x-block, pool half per y; wave w covers 128 pool rows.
__global__ __launch_bounds__(256) void k_poolmax(
    const u16* __restrict__ f, const u16* __restrict__ spr,
    const u16* __restrict__ pag, const u16* __restrict__ psp,
    u32* __restrict__ RfK, u32* __restrict__ RsK) {
    int tid = threadIdx.x;
    int lane = tid & 63, w = tid >> 6;
    int half = lane >> 5, li = lane & 31;
    int i0 = blockIdx.x * 32;

    bf16x8 brf[8], brs[8];
#pragma unroll
    for (int kc = 0; kc < 8; ++kc) {
        int koff = kc * 16 + half * 8;
        brf[kc] = ldfrag(f, i0 + li, koff);
        brs[kc] = ldfrag(spr, i0 + li, koff);
    }

    float rmf = -1e30f, rms = -1e30f;
    int j0w = blockIdx.y * 512 + w * 128;
    for (int jt = 0; jt < 4; ++jt) {
        int j0 = j0w + jt * 32;
        f32x16 accf = {}; f32x16 accs = {};
#pragma unroll
        for (int kc = 0; kc < 8; ++kc) {
            int koff = kc * 16 + half * 8;
            bf16x8 paf = ldfrag(pag, j0 + li, koff);
            bf16x8 psf = ldfrag(psp, j0 + li, koff);
            accf = __builtin_amdgcn_mfma_f32_32x32x16_bf16(paf, brf[kc], accf, 0, 0, 0);
            accs = __builtin_amdgcn_mfma_f32_32x32x16_bf16(psf, brs[kc], accs, 0, 0, 0);
        }
#pragma unroll
        for (int r = 0; r < 16; ++r) {
            rmf = fmaxf(rmf, accf[r]);
            rms = fmaxf(rms, accs[r]);
        }
    }
    rmf = fmaxf(rmf, __shfl_xor(rmf, 32, 64));
    rms = fmaxf(rms, __shfl_xor(rms, 32, 64));

    __shared__ float red[2][4][32];
    if (half == 0) { red[0][w][li] = rmf; red[1][w][li] = rms; }
    __syncthreads();
    if (tid < 64) {
        int p = tid >> 5, ii = tid & 31;
        float m = red[p][0][ii];
        m = fmaxf(m, red[p][1][ii]);
        m = fmaxf(m, red[p][2][ii]);
        m = fmaxf(m, red[p][3][ii]);
        atomicMax((p ? RsK : RfK) + i0 + ii, fkey(m));
    }
}

// ---------------- Kernel 2: main fused two-pass kernel ----------------
// grid (32, 32): 128 i per block (4 waves x 32), 128-j chunk (4 tiles of 32 j).
// Pass 0 (steps 0-3): f,s_pr resident -> mask bits (4b/pair) into LDS.
// Pass 1 (steps 4-7): z,zmix resident -> consume bits, accumulate 6 stats, atomicAdd into P.
__global__ __launch_bounds__(256) void k_main(
    const u16* __restrict__ zp, const u16* __restrict__ sp,
    const u16* __restrict__ fp, const u16* __restrict__ xp,
    const float* __restrict__ mnb,
    const u32* __restrict__ RfK, const u32* __restrict__ RsK,
    float* __restrict__ P /* [4096][8] */) {
    __shared__ u16 stile[2 * 32 * 144];   // 2 mats x 32 rows x 144-elem padded stride = 18432 B
    __shared__ u64 sbits[4 * 256];        // [jt][tid] packed masks, 8192 B

    int tid = threadIdx.x;
    int lane = tid & 63, w = tid >> 6;
    int half = lane >> 5, li = lane & 31;
    int i = blockIdx.x * 128 + w * 32 + li;
    int cbase = blockIdx.y * 128;

    // staging decomposition: it in 0..3, mat = it>>1, row = (it&1)*16 + (tid>>4), c16 = tid&15
    int srow_lo = tid >> 4;
    int sc16 = tid & 15;

    // resident fragments, pass 0: slot0 = f, slot1 = s_pr
    bf16x8 bres[2][8];
#pragma unroll
    for (int kc = 0; kc < 8; ++kc) {
        bres[0][kc] = ldfrag(fp, i, kc * 16 + half * 8);
        bres[1][kc] = ldfrag(sp, i, kc * 16 + half * 8);
    }

    float rfi = keyf(RfK[i]), rsi = keyf(RsK[i]);
    const float* mrow = mnb + (size_t)(i & 255) * 4096;
    float wsum = 0.f, ones = 0.f, Az = 0.f, Ax = 0.f, Zz = 0.f, Zx = 0.f;
    const float c1 = TEMP_INV * LOG2E;

    uint4 pf[4];
    // prefetch step 0 tile (pass 0, jt 0)
#pragma unroll
    for (int it = 0; it < 4; ++it) {
        const u16* mp = (it >> 1) ? sp : fp;
        int r = (it & 1) * 16 + srow_lo;
        pf[it] = *(const uint4*)(mp + (size_t)(cbase + r) * 128 + sc16 * 8);
    }

    for (int step = 0; step < 8; ++step) {
        int jt = step & 3;
        int j0 = cbase + jt * 32;

        __syncthreads();  // previous tile fully consumed
#pragma unroll
        for (int it = 0; it < 4; ++it) {
            int r = (it & 1) * 16 + srow_lo;
            *(uint4*)(stile + (it >> 1) * 4608 + r * 144 + sc16 * 8) = pf[it];
        }
        __syncthreads();

        if (step + 1 < 8) {  // prefetch next tile while computing
            int ps = (step + 1) >> 2, pj0 = cbase + ((step + 1) & 3) * 32;
            const u16* m0 = ps ? zp : fp;
            const u16* m1 = ps ? xp : sp;
#pragma unroll
            for (int it = 0; it < 4; ++it) {
                const u16* mp = (it >> 1) ? m1 : m0;
                int r = (it & 1) * 16 + srow_lo;
                pf[it] = *(const uint4*)(mp + (size_t)(pj0 + r) * 128 + sc16 * 8);
            }
        }

        if (step < 4) {
            // ---- pass 0: mask sims ----
            f32x16 accF = {}; f32x16 accS = {};
#pragma unroll
            for (int kc = 0; kc < 8; ++kc) {
                const u16* ab = stile + li * 144 + kc * 16 + half * 8;
                bf16x8 a0 = *(const bf16x8*)ab;
                bf16x8 a1 = *(const bf16x8*)(ab + 4608);
                accF = __builtin_amdgcn_mfma_f32_32x32x16_bf16(a0, bres[0][kc], accF, 0, 0, 0);
                accS = __builtin_amdgcn_mfma_f32_32x32x16_bf16(a1, bres[1][kc], accS, 0, 0, 0);
            }
            // elem r: j = j0 + (r&3) + 8*(r>>2) + 4*half  (m74/m101 C/D layout)
            u64 bits = 0;
#pragma unroll
            for (int q = 0; q < 4; ++q) {
                int jb = j0 + q * 8 + half * 4;
                uint4 kf4 = *(const uint4*)(RfK + jb);
                uint4 ks4 = *(const uint4*)(RsK + jb);
                f32x4 mb4 = *(const f32x4*)(mrow + jb);
#pragma unroll
                for (int t = 0; t < 4; ++t) {
                    int r = q * 4 + t;
                    int j = jb + t;
                    bool nm = (j != i);
                    float rfj = keyf(((const u32*)&kf4)[t]);
                    float rsj = keyf(((const u32*)&ks4)[t]);
                    bool mob = accF[r] > fminf(rfi, rfj);
                    bool meb = accS[r] > fminf(rsi, rsj);
                    bool mnbv = mb4[t] > 0.0f;
                    u32 e = ((mob && nm) ? 1u : 0u) | ((meb && nm) ? 2u : 0u) |
                            (((mob || mnbv) && nm) ? 4u : 0u);
                    bits |= (u64)e << (4 * r);
                }
            }
            sbits[jt * 256 + tid] = bits;
            if (step == 3) {  // swap residents to z,zmix for pass 1
#pragma unroll
                for (int kc = 0; kc < 8; ++kc) {
                    bres[0][kc] = ldfrag(zp, i, kc * 16 + half * 8);
                    bres[1][kc] = ldfrag(xp, i, kc * 16 + half * 8);
                }
            }
        } else {
            // ---- pass 1: log-prob sims + consume masks ----
            f32x16 accZ = {}; f32x16 accX = {};
#pragma unroll
            for (int kc = 0; kc < 8; ++kc) {
                const u16* ab = stile + li * 144 + kc * 16 + half * 8;
                bf16x8 a0 = *(const bf16x8*)ab;
                bf16x8 a1 = *(const bf16x8*)(ab + 4608);
                accZ = __builtin_amdgcn_mfma_f32_32x32x16_bf16(a0, bres[0][kc], accZ, 0, 0, 0);
                accX = __builtin_amdgcn_mfma_f32_32x32x16_bf16(a1, bres[1][kc], accX, 0, 0, 0);
            }
            u64 bits = sbits[jt * 256 + tid];
#pragma unroll
            for (int r = 0; r < 16; ++r) {
                u32 e = (u32)(bits >> (4 * r)) & 7u;
                float w1 = (e & 1u) ? 1.0f : 0.0f;
                float wv = w1 + ((e & 2u) ? 0.5f : 0.0f);
                float ng = (e & 4u) ? 1.0f : 0.0f;
                float lvz = accZ[r], lvx = accX[r];
                wsum += wv; ones += w1;
                Az = fmaf(wv, lvz, Az);
                Ax = fmaf(wv, lvx, Ax);
                Zz = fmaf(ng, EXP2(fmaf(lvz, c1, -c1)), Zz);
                Zx = fmaf(ng, EXP2(fmaf(lvx, c1, -c1)), Zx);
            }
        }
    }

    // combine two lane-halves (disjoint j sets, same i), then atomic into P
    wsum += __shfl_xor(wsum, 32, 64);
    ones += __shfl_xor(ones, 32, 64);
    Az += __shfl_xor(Az, 32, 64);
    Ax += __shfl_xor(Ax, 32, 64);
    Zz += __shfl_xor(Zz, 32, 64);
    Zx += __shfl_xor(Zx, 32, 64);
    if (half == 0) {
        float* pr = P + (size_t)i * 8;
        atomicAdd(pr + 0, wsum);
        atomicAdd(pr + 1, ones);
        atomicAdd(pr + 2, Az);
        atomicAdd(pr + 3, Ax);
        atomicAdd(pr + 4, Zz);
        atomicAdd(pr + 5, Zx);
    }
}

// ---------------- Kernel 3: per-m block means + ticketed final sum ----------------
__global__ __launch_bounds__(256) void k_final(const float* __restrict__ P,
                                               float* __restrict__ accum, u32* __restrict__ ticket,
                                               u32* __restrict__ out) {
    int t = threadIdx.x, m = blockIdx.x;
    int i = m * 256 + t;
    f32x4 a = *(const f32x4*)(P + (size_t)i * 8);
    f32x4 b = *(const f32x4*)(P + (size_t)i * 8 + 4);
    float wsum = a[0], ones = a[1], Az = a[2], Ax = a[3], Zz = b[0], Zx = b[1];
    float dw = wsum > 0.f ? wsum : 1.0f;
    float lz = Zz > 0.f ? logf(Zz) : 0.f;
    float lx = Zx > 0.f ? logf(Zx) : 0.f;
    float mlz = (TEMP_INV * Az - wsum * (TEMP_INV + lz)) / dw;
    float mlx = (TEMP_INV * Ax - wsum * (TEMP_INV + lx)) / dw;
    float si = ones > 0.f ? wsum : 0.f;
    float ci = (mlz + mlx) * si;
#pragma unroll
    for (int d = 1; d < 64; d <<= 1) {
        ci += __shfl_xor(ci, d, 64);
        si += __shfl_xor(si, d, 64);
    }
    __shared__ float rc[4], rs[4];
    int wv = t >> 6;
    if ((t & 63) == 0) { rc[wv] = ci; rs[wv] = si; }
    __syncthreads();
    if (t == 0) {
        float cs = rc[0] + rc[1] + rc[2] + rc[3];
        float ss = rs[0] + rs[1] + rs[2] + rs[3];
        float ratio = ss > 0.f ? cs / ss : 0.f;
        atomicAdd(accum, ratio);
        __threadfence();
        u32 old = atomicAdd(ticket, 1u);
        if (old == 15u) {
            float total = atomicAdd(accum, 0.0f);  // returns final sum (all 16 adds done)
            __hip_bfloat16 hb = __float2bfloat16(-total / 32.0f);
            u32 bits = (u32)__bfloat16_as_ushort(hb);
            out[0] = (bits << 16) | bits;  // bf16/f32 dual-interpretation hedge (passed r3)
        }
    }
}

extern "C" void kernel_launch(void* const* d_in, const int* in_sizes, int n_in,
                              void* d_out, int out_size, void* d_ws, size_t ws_size,
                              hipStream_t stream) {
    const float* z   = (const float*)d_in[0];
    const float* spr = (const float*)d_in[1];
    const float* f   = (const float*)d_in[2];
    const float* pag = (const float*)d_in[3];
    const float* psp = (const float*)d_in[4];
    const float* zmx = (const float*)d_in[5];
    const float* mnb = (const float*)d_in[6];

    // ws: bf16 features [TOT_CONV u16] | P[4096][8] f32 | RfK[4096] | RsK[4096] | accum,ticket
    u16* cb = (u16*)d_ws;
    u16* zb   = cb;
    u16* sprb = cb + N_Z;
    u16* fb   = cb + 2 * N_Z;
    u16* pagb = cb + 3 * N_Z;
    u16* pspb = cb + 3 * N_Z + N_POOL;
    u16* zmxb = cb + 3 * N_Z + 2 * N_POOL;
    float* P   = (float*)(cb + TOT_CONV);
    u32* RfK   = (u32*)((char*)P + 131072);
    u32* RsK   = RfK + 4096;
    float* accum = (float*)(RsK + 4096);
    u32* ticket  = (u32*)(accum + 1);

    k_convert<<<CONV_BLKS + ZERO_BLKS, 256, 0, stream>>>(z, spr, f, pag, psp, zmx, cb);
    k_poolmax<<<dim3(128, 2), 256, 0, stream>>>(fb, sprb, pagb, pspb, RfK, RsK);
    k_main<<<dim3(32, 32), 256, 0, stream>>>(zb, sprb, fb, zmxb, mnb, RfK, RsK, P);
    k_final<<<16, 256, 0, stream>>>(P, accum, ticket, (u32*)d_out);
}

// Round 6
// 159.870 us; speedup vs baseline: 1.1156x; 1.0860x over previous
//
#include <hip/hip_runtime.h>
#include <hip/hip_bf16.h>

typedef unsigned short u16;
typedef unsigned int u32;
typedef unsigned long long u64;
typedef __bf16 bf16x8 __attribute__((ext_vector_type(8)));
typedef float f32x16 __attribute__((ext_vector_type(16)));
typedef float f32x4 __attribute__((ext_vector_type(4)));

#define TEMP_INV (1.0f / 0.07f)
#define LOG2E 1.4426950408889634f

#if __has_builtin(__builtin_amdgcn_exp2f)
#define EXP2(x) __builtin_amdgcn_exp2f(x)
#else
#define EXP2(x) exp2f(x)
#endif

#define N_Z   524288    // 4096*128
#define N_POOL 131072   // 1024*128
#define TOT_CONV 2359296
#define CONV_BLKS 2304
#define P_BYTES 1572864   // 16 chunks * 6 stats * 4096 * 4B
#define ZB_BYTES 32776    // RfK(16384) + RsK(16384) + accum(4) + ticket(4)
#define ZERO_BLKS 9

// ordered-key encode for atomic max on float (monotone u32 map)
__device__ __forceinline__ u32 fkey(float f) {
    u32 u = __float_as_uint(f);
    return (u & 0x80000000u) ? ~u : (u | 0x80000000u);
}
__device__ __forceinline__ float keyf(u32 k) {
    u32 u = (k & 0x80000000u) ? (k ^ 0x80000000u) : ~k;
    return __uint_as_float(u);
}

// global fragment load: row-major [.,128], lane li holds row, k = koff..koff+7
__device__ __forceinline__ bf16x8 ldfrag(const u16* __restrict__ base, int row, int koff) {
    return *(const bf16x8*)(base + (size_t)row * 128 + koff);
}

// LDS tile: 2 mats x 32 rows x 136-u16 stride (272 B = 17*16 B, odd 16B multiple -> b128 conflict-free)
#define TSTRIDE 136
#define TMAT 4352   // 32*136 u16 per mat

// ---------------- Kernel 0: f32->bf16 convert + zero keys/accum/ticket ----------------
__global__ __launch_bounds__(256) void k_convert(
    const float* __restrict__ z, const float* __restrict__ spr,
    const float* __restrict__ f, const float* __restrict__ pag,
    const float* __restrict__ psp, const float* __restrict__ zmx,
    u16* __restrict__ dst) {
    int bid = blockIdx.x;
    if (bid >= CONV_BLKS) {
        size_t byte = ((size_t)(bid - CONV_BLKS) * 256 + threadIdx.x) * 16;
        if (byte < ZB_BYTES) {
            uint4 zero = {0, 0, 0, 0};
            *(uint4*)((char*)dst + (size_t)TOT_CONV * 2 + P_BYTES + byte) = zero;
        }
        return;
    }
    size_t e0 = ((size_t)bid * 256 + threadIdx.x) * 4;
    const float* src; size_t off;
    if (e0 < N_Z)                       { src = z;   off = e0; }
    else if (e0 < 2 * N_Z)              { src = spr; off = e0 - N_Z; }
    else if (e0 < 3 * N_Z)              { src = f;   off = e0 - 2 * N_Z; }
    else if (e0 < 3 * N_Z + N_POOL)     { src = pag; off = e0 - 3 * N_Z; }
    else if (e0 < 3 * N_Z + 2 * N_POOL) { src = psp; off = e0 - (3 * N_Z + N_POOL); }
    else                                { src = zmx; off = e0 - (3 * N_Z + 2 * N_POOL); }
    f32x4 v = *(const f32x4*)(src + off);
    ushort4 o;
    o.x = __bfloat16_as_ushort(__float2bfloat16(v[0]));
    o.y = __bfloat16_as_ushort(__float2bfloat16(v[1]));
    o.z = __bfloat16_as_ushort(__float2bfloat16(v[2]));
    o.w = __bfloat16_as_ushort(__float2bfloat16(v[3]));
    *(ushort4*)(dst + e0) = o;
}

// ---------------- Kernel 1: pool maxes, cooperative LDS staging ----------------
// grid (32, 16): 128 i rows per block (4 waves x 32), 64-pool-row chunk (2 tiles).
__global__ __launch_bounds__(256) void k_poolmax(
    const u16* __restrict__ f, const u16* __restrict__ spr,
    const u16* __restrict__ pag, const u16* __restrict__ psp,
    u32* __restrict__ RfK, u32* __restrict__ RsK) {
    __shared__ u16 stile[2 * TMAT];

    int tid = threadIdx.x;
    int lane = tid & 63, w = tid >> 6;
    int half = lane >> 5, li = lane & 31;
    int i = blockIdx.x * 128 + w * 32 + li;
    int pbase = blockIdx.y * 64;
    int srow = tid >> 4, sc16 = tid & 15;   // rows staged: srow and srow+16

    bf16x8 brf[8], brs[8];
#pragma unroll
    for (int kc = 0; kc < 8; ++kc) {
        int koff = kc * 16 + half * 8;
        brf[kc] = ldfrag(f, i, koff);
        brs[kc] = ldfrag(spr, i, koff);
    }

    uint4 pf[2][2];   // [mat][rowhalf]
    pf[0][0] = *(const uint4*)(pag + (size_t)(pbase + srow) * 128 + sc16 * 8);
    pf[0][1] = *(const uint4*)(pag + (size_t)(pbase + srow + 16) * 128 + sc16 * 8);
    pf[1][0] = *(const uint4*)(psp + (size_t)(pbase + srow) * 128 + sc16 * 8);
    pf[1][1] = *(const uint4*)(psp + (size_t)(pbase + srow + 16) * 128 + sc16 * 8);

    float rmf = -1e30f, rms = -1e30f;
#pragma unroll
    for (int jt = 0; jt < 2; ++jt) {
        __syncthreads();
        *(uint4*)(stile + (size_t)srow * TSTRIDE + sc16 * 8) = pf[0][0];
        *(uint4*)(stile + (size_t)(srow + 16) * TSTRIDE + sc16 * 8) = pf[0][1];
        *(uint4*)(stile + TMAT + (size_t)srow * TSTRIDE + sc16 * 8) = pf[1][0];
        *(uint4*)(stile + TMAT + (size_t)(srow + 16) * TSTRIDE + sc16 * 8) = pf[1][1];
        __syncthreads();
        if (jt == 0) {
            pf[0][0] = *(const uint4*)(pag + (size_t)(pbase + 32 + srow) * 128 + sc16 * 8);
            pf[0][1] = *(const uint4*)(pag + (size_t)(pbase + 48 + srow) * 128 + sc16 * 8);
            pf[1][0] = *(const uint4*)(psp + (size_t)(pbase + 32 + srow) * 128 + sc16 * 8);
            pf[1][1] = *(const uint4*)(psp + (size_t)(pbase + 48 + srow) * 128 + sc16 * 8);
        }
        f32x16 accf = {}; f32x16 accs = {};
#pragma unroll
        for (int kc = 0; kc < 8; ++kc) {
            const u16* ab = stile + li * TSTRIDE + kc * 16 + half * 8;
            bf16x8 a0 = *(const bf16x8*)ab;
            bf16x8 a1 = *(const bf16x8*)(ab + TMAT);
            accf = __builtin_amdgcn_mfma_f32_32x32x16_bf16(a0, brf[kc], accf, 0, 0, 0);
            accs = __builtin_amdgcn_mfma_f32_32x32x16_bf16(a1, brs[kc], accs, 0, 0, 0);
        }
#pragma unroll
        for (int r = 0; r < 16; ++r) {
            rmf = fmaxf(rmf, accf[r]);
            rms = fmaxf(rms, accs[r]);
        }
    }
    rmf = fmaxf(rmf, __shfl_xor(rmf, 32, 64));
    rms = fmaxf(rms, __shfl_xor(rms, 32, 64));
    if (half == 0) {
        atomicMax(RfK + i, fkey(rmf));
        atomicMax(RsK + i, fkey(rms));
    }
}

// ---------------- Kernel 2: main fused two-pass kernel ----------------
// grid (32, 16): 128 i per block (4 waves x 32), 256-j chunk (8 tiles of 32 j).
// Pass 0: f,s_pr resident -> mask bits (4b/pair) kept in 8 u64 REGISTERS.
// Pass 1: z,zmix resident -> consume bits, accumulate 6 stats, chunk-partial stores (NO atomics).
__global__ __launch_bounds__(256) void k_main(
    const u16* __restrict__ zp, const u16* __restrict__ sp,
    const u16* __restrict__ fp, const u16* __restrict__ xp,
    const float* __restrict__ mnb,
    const u32* __restrict__ RfK, const u32* __restrict__ RsK,
    float* __restrict__ P /* [16][6][4096] */) {
    __shared__ u16 stile[2 * TMAT];   // 17408 B

    int tid = threadIdx.x;
    int lane = tid & 63, w = tid >> 6;
    int half = lane >> 5, li = lane & 31;
    int i = blockIdx.x * 128 + w * 32 + li;
    int cbase = blockIdx.y * 256;
    int srow = tid >> 4, sc16 = tid & 15;   // rows staged: srow and srow+16

    bf16x8 bres0[8], bres1[8];
#pragma unroll
    for (int kc = 0; kc < 8; ++kc) {
        int koff = kc * 16 + half * 8;
        bres0[kc] = ldfrag(fp, i, koff);
        bres1[kc] = ldfrag(sp, i, koff);
    }

    float rfi = keyf(RfK[i]), rsi = keyf(RsK[i]);
    const float* mrow = mnb + (size_t)(i & 255) * 4096;
    float wsum = 0.f, ones = 0.f, Az = 0.f, Ax = 0.f, Zz = 0.f, Zx = 0.f;
    const float c1 = TEMP_INV * LOG2E;
    u64 bitsv[8];

    uint4 pf[2][2];
    pf[0][0] = *(const uint4*)(fp + (size_t)(cbase + srow) * 128 + sc16 * 8);
    pf[0][1] = *(const uint4*)(fp + (size_t)(cbase + srow + 16) * 128 + sc16 * 8);
    pf[1][0] = *(const uint4*)(sp + (size_t)(cbase + srow) * 128 + sc16 * 8);
    pf[1][1] = *(const uint4*)(sp + (size_t)(cbase + srow + 16) * 128 + sc16 * 8);

    // ---- pass 0: mask sims ----
#pragma unroll
    for (int jt = 0; jt < 8; ++jt) {
        int j0 = cbase + jt * 32;
        __syncthreads();
        *(uint4*)(stile + (size_t)srow * TSTRIDE + sc16 * 8) = pf[0][0];
        *(uint4*)(stile + (size_t)(srow + 16) * TSTRIDE + sc16 * 8) = pf[0][1];
        *(uint4*)(stile + TMAT + (size_t)srow * TSTRIDE + sc16 * 8) = pf[1][0];
        *(uint4*)(stile + TMAT + (size_t)(srow + 16) * TSTRIDE + sc16 * 8) = pf[1][1];
        __syncthreads();
        {   // prefetch next tile (last pass-0 iter prefetches pass-1 tile 0)
            const u16* m0 = (jt < 7) ? fp : zp;
            const u16* m1 = (jt < 7) ? sp : xp;
            int pj0 = cbase + ((jt + 1) & 7) * 32;
            pf[0][0] = *(const uint4*)(m0 + (size_t)(pj0 + srow) * 128 + sc16 * 8);
            pf[0][1] = *(const uint4*)(m0 + (size_t)(pj0 + srow + 16) * 128 + sc16 * 8);
            pf[1][0] = *(const uint4*)(m1 + (size_t)(pj0 + srow) * 128 + sc16 * 8);
            pf[1][1] = *(const uint4*)(m1 + (size_t)(pj0 + srow + 16) * 128 + sc16 * 8);
        }
        f32x16 accF = {}; f32x16 accS = {};
#pragma unroll
        for (int kc = 0; kc < 8; ++kc) {
            const u16* ab = stile + li * TSTRIDE + kc * 16 + half * 8;
            bf16x8 a0 = *(const bf16x8*)ab;
            bf16x8 a1 = *(const bf16x8*)(ab + TMAT);
            accF = __builtin_amdgcn_mfma_f32_32x32x16_bf16(a0, bres0[kc], accF, 0, 0, 0);
            accS = __builtin_amdgcn_mfma_f32_32x32x16_bf16(a1, bres1[kc], accS, 0, 0, 0);
        }
        // elem r: j = j0 + (r&3) + 8*(r>>2) + 4*half  (m74/m101 C/D layout)
        u64 bits = 0;
#pragma unroll
        for (int q = 0; q < 4; ++q) {
            int jb = j0 + q * 8 + half * 4;
            uint4 kf4 = *(const uint4*)(RfK + jb);
            uint4 ks4 = *(const uint4*)(RsK + jb);
            f32x4 mb4 = *(const f32x4*)(mrow + jb);
#pragma unroll
            for (int t = 0; t < 4; ++t) {
                int r = q * 4 + t;
                int j = jb + t;
                bool nm = (j != i);
                float rfj = keyf(((const u32*)&kf4)[t]);
                float rsj = keyf(((const u32*)&ks4)[t]);
                bool mob = accF[r] > fminf(rfi, rfj);
                bool meb = accS[r] > fminf(rsi, rsj);
                bool mnbv = mb4[t] > 0.0f;
                u32 e = ((mob && nm) ? 1u : 0u) | ((meb && nm) ? 2u : 0u) |
                        (((mob || mnbv) && nm) ? 4u : 0u);
                bits |= (u64)e << (4 * r);
            }
        }
        bitsv[jt] = bits;
    }

    // swap residents to z,zmix
#pragma unroll
    for (int kc = 0; kc < 8; ++kc) {
        int koff = kc * 16 + half * 8;
        bres0[kc] = ldfrag(zp, i, koff);
        bres1[kc] = ldfrag(xp, i, koff);
    }

    // ---- pass 1: log-prob sims + consume masks ----
#pragma unroll
    for (int jt = 0; jt < 8; ++jt) {
        __syncthreads();
        *(uint4*)(stile + (size_t)srow * TSTRIDE + sc16 * 8) = pf[0][0];
        *(uint4*)(stile + (size_t)(srow + 16) * TSTRIDE + sc16 * 8) = pf[0][1];
        *(uint4*)(stile + TMAT + (size_t)srow * TSTRIDE + sc16 * 8) = pf[1][0];
        *(uint4*)(stile + TMAT + (size_t)(srow + 16) * TSTRIDE + sc16 * 8) = pf[1][1];
        __syncthreads();
        if (jt < 7) {
            int pj0 = cbase + (jt + 1) * 32;
            pf[0][0] = *(const uint4*)(zp + (size_t)(pj0 + srow) * 128 + sc16 * 8);
            pf[0][1] = *(const uint4*)(zp + (size_t)(pj0 + srow + 16) * 128 + sc16 * 8);
            pf[1][0] = *(const uint4*)(xp + (size_t)(pj0 + srow) * 128 + sc16 * 8);
            pf[1][1] = *(const uint4*)(xp + (size_t)(pj0 + srow + 16) * 128 + sc16 * 8);
        }
        f32x16 accZ = {}; f32x16 accX = {};
#pragma unroll
        for (int kc = 0; kc < 8; ++kc) {
            const u16* ab = stile + li * TSTRIDE + kc * 16 + half * 8;
            bf16x8 a0 = *(const bf16x8*)ab;
            bf16x8 a1 = *(const bf16x8*)(ab + TMAT);
            accZ = __builtin_amdgcn_mfma_f32_32x32x16_bf16(a0, bres0[kc], accZ, 0, 0, 0);
            accX = __builtin_amdgcn_mfma_f32_32x32x16_bf16(a1, bres1[kc], accX, 0, 0, 0);
        }
        u64 bits = bitsv[jt];
#pragma unroll
        for (int r = 0; r < 16; ++r) {
            u32 e = (u32)(bits >> (4 * r)) & 7u;
            float w1 = (e & 1u) ? 1.0f : 0.0f;
            float wv = w1 + ((e & 2u) ? 0.5f : 0.0f);
            float ng = (e & 4u) ? 1.0f : 0.0f;
            float lvz = accZ[r], lvx = accX[r];
            wsum += wv; ones += w1;
            Az = fmaf(wv, lvz, Az);
            Ax = fmaf(wv, lvx, Ax);
            Zz = fmaf(ng, EXP2(fmaf(lvz, c1, -c1)), Zz);
            Zx = fmaf(ng, EXP2(fmaf(lvx, c1, -c1)), Zx);
        }
    }

    // combine two lane-halves (disjoint j sets, same i); coalesced SoA partial store
    wsum += __shfl_xor(wsum, 32, 64);
    ones += __shfl_xor(ones, 32, 64);
    Az += __shfl_xor(Az, 32, 64);
    Ax += __shfl_xor(Ax, 32, 64);
    Zz += __shfl_xor(Zz, 32, 64);
    Zx += __shfl_xor(Zx, 32, 64);
    if (half == 0) {
        float* pb = P + ((size_t)blockIdx.y * 6) * 4096 + i;
        pb[0] = wsum;
        pb[4096] = ones;
        pb[2 * 4096] = Az;
        pb[3 * 4096] = Ax;
        pb[4 * 4096] = Zz;
        pb[5 * 4096] = Zx;
    }
}

// ---------------- Kernel 3: reduce 16 chunks, per-m block means, ticketed final sum ----------------
__global__ __launch_bounds__(256) void k_final(const float* __restrict__ P,
                                               float* __restrict__ accum, u32* __restrict__ ticket,
                                               u32* __restrict__ out) {
    int t = threadIdx.x;
    int i = blockIdx.x * 256 + t;
    float wsum = 0.f, ones = 0.f, Az = 0.f, Ax = 0.f, Zz = 0.f, Zx = 0.f;
#pragma unroll
    for (int c = 0; c < 16; ++c) {
        const float* pb = P + ((size_t)c * 6) * 4096 + i;
        wsum += pb[0];
        ones += pb[4096];
        Az += pb[2 * 4096];
        Ax += pb[3 * 4096];
        Zz += pb[4 * 4096];
        Zx += pb[5 * 4096];
    }
    float dw = wsum > 0.f ? wsum : 1.0f;
    float lz = Zz > 0.f ? logf(Zz) : 0.f;
    float lx = Zx > 0.f ? logf(Zx) : 0.f;
    float mlz = (TEMP_INV * Az - wsum * (TEMP_INV + lz)) / dw;
    float mlx = (TEMP_INV * Ax - wsum * (TEMP_INV + lx)) / dw;
    float si = ones > 0.f ? wsum : 0.f;
    float ci = (mlz + mlx) * si;
#pragma unroll
    for (int d = 1; d < 64; d <<= 1) {
        ci += __shfl_xor(ci, d, 64);
        si += __shfl_xor(si, d, 64);
    }
    __shared__ float rc[4], rs[4];
    int wv = t >> 6;
    if ((t & 63) == 0) { rc[wv] = ci; rs[wv] = si; }
    __syncthreads();
    if (t == 0) {
        float cs = rc[0] + rc[1] + rc[2] + rc[3];
        float ss = rs[0] + rs[1] + rs[2] + rs[3];
        float ratio = ss > 0.f ? cs / ss : 0.f;
        atomicAdd(accum, ratio);
        __threadfence();
        u32 old = atomicAdd(ticket, 1u);
        if (old == 15u) {
            float total = atomicAdd(accum, 0.0f);  // all 16 adds complete
            __hip_bfloat16 hb = __float2bfloat16(-total / 32.0f);
            u32 bits = (u32)__bfloat16_as_ushort(hb);
            out[0] = (bits << 16) | bits;  // bf16/f32 dual-interpretation hedge (passed r3/r4)
        }
    }
}

extern "C" void kernel_launch(void* const* d_in, const int* in_sizes, int n_in,
                              void* d_out, int out_size, void* d_ws, size_t ws_size,
                              hipStream_t stream) {
    const float* z   = (const float*)d_in[0];
    const float* spr = (const float*)d_in[1];
    const float* f   = (const float*)d_in[2];
    const float* pag = (const float*)d_in[3];
    const float* psp = (const float*)d_in[4];
    const float* zmx = (const float*)d_in[5];
    const float* mnb = (const float*)d_in[6];

    // ws: bf16 features [TOT_CONV u16] | P[16][6][4096] f32 | RfK[4096] | RsK[4096] | accum | ticket
    u16* cb = (u16*)d_ws;
    u16* zb   = cb;
    u16* sprb = cb + N_Z;
    u16* fb   = cb + 2 * N_Z;
    u16* pagb = cb + 3 * N_Z;
    u16* pspb = cb + 3 * N_Z + N_POOL;
    u16* zmxb = cb + 3 * N_Z + 2 * N_POOL;
    float* P     = (float*)(cb + TOT_CONV);
    u32* RfK     = (u32*)((char*)P + P_BYTES);
    u32* RsK     = RfK + 4096;
    float* accum = (float*)(RsK + 4096);
    u32* ticket  = (u32*)(accum + 1);

    k_convert<<<CONV_BLKS + ZERO_BLKS, 256, 0, stream>>>(z, spr, f, pag, psp, zmx, cb);
    k_poolmax<<<dim3(32, 16), 256, 0, stream>>>(fb, sprb, pagb, pspb, RfK, RsK);
    k_main<<<dim3(32, 16), 256, 0, stream>>>(zb, sprb, fb, zmxb, mnb, RfK, RsK, P);
    k_final<<<16, 256, 0, stream>>>(P, accum, ticket, (u32*)d_out);
}